// Round 15
// baseline (77.364 us; speedup 1.0000x reference)
//
#include <hip/hip_runtime.h>

// T=2^21 sequential nonlinear storage recurrence + per-column z-score.
// R15 = R14 with the nontemporal-store compile fix (clang ext_vector f4 alias;
// HIP float4 is a class type the builtin rejects). Content unchanged:
//  - tail FSTEP 21->14 VALU (divisor corrections dropped; biases cancel)
//  - NCOARSE 40->32, WPAD 40
//  - normalize: nontemporal stores for out (48MB write-once)

#define T_TOTAL   (1 << 21)
#define L_CHUNK   16
#define C_CHUNKS  (T_TOTAL / L_CHUNK)        // 131072 chunks == windows
#define NCOARSE   32
#define NTAIL     128
#define WPAD      40                         // NCOARSE + NTAIL/16
#define THREADS   256
#define NBLOCKS   (C_CHUNKS / THREADS)       // 512 -> 2 blocks/CU, 2 waves/SIMD
#define LDSN      4256                       // float2 slots (need 4240)
#define NSTAGE    2120                       // float4s per block window
#define X4MAX     (T_TOTAL / 2 - 1)
#define C49       0.44444445f

typedef float f4nt __attribute__((ext_vector_type(4)));

// ws layout (bytes)
#define OFF_PP    0                                   // [8][512] double
#define OFF_SP    32768                               // [4][512] double
#define OFF_MUSIG 49152                               // 12 float
#define OFF_S4    49664                               // (WPAD+C) float4
#define OFF_SIDE  (OFF_S4 + (WPAD + C_CHUNKS) * 16)   // T float2 (ps,perc)

#define SWZ(w) ((w) ^ (((w) >> 4) & 31))

// ---------------- pre-pass: per-window sufficient statistics (r-units) ----
__global__ __launch_bounds__(256, 2) void prepass_kernel(const float4* __restrict__ x4,
                                                         const float* __restrict__ x1p,
                                                         float4* __restrict__ s4,
                                                         double* __restrict__ pp) {
    const float x1s    = x1p[0];
    const float inv_x1 = 1.0f / x1s;
    const int w = blockIdx.x * 256 + threadIdx.x;     // window id
    const float4* px = x4 + 8 * (size_t)w;

    float Tp = 0, Qp = 0, Te = 0, Qe = 0;
    float s0 = 0, s1 = 0, s2c = 0, s3 = 0, q0 = 0, q1 = 0, q2 = 0, q3 = 0;
#pragma unroll
    for (int q = 0; q < 8; ++q) {
        float4 v = px[q];
        float pn0 = fmaxf(v.x - v.y, 0.0f), en0 = fmaxf(v.y - v.x, 0.0f);
        float pn1 = fmaxf(v.z - v.w, 0.0f), en1 = fmaxf(v.w - v.z, 0.0f);
        float a0 = pn0 * inv_x1, b0 = en0 * inv_x1;
        float a1 = pn1 * inv_x1, b1 = en1 * inv_x1;
        float tp0 = a0 * fmaf(a0 * a0, -0.33333334f, 1.0f);
        float te0 = b0 * fmaf(b0 * b0, -0.33333334f, 1.0f);
        float tp1 = a1 * fmaf(a1 * a1, -0.33333334f, 1.0f);
        float te1 = b1 * fmaf(b1 * b1, -0.33333334f, 1.0f);
        Tp += tp0 + tp1;  Te += te0 + te1;
        Qp = fmaf(tp0, tp0, Qp); Qp = fmaf(tp1, tp1, Qp);
        Qe = fmaf(te0, te0, Qe); Qe = fmaf(te1, te1, Qe);
        s0 += v.x + v.z; q0 = fmaf(v.x, v.x, q0); q0 = fmaf(v.z, v.z, q0);
        s1 += v.y + v.w; q1 = fmaf(v.y, v.y, q1); q1 = fmaf(v.w, v.w, q1);
        s2c += pn0 + pn1; q2 = fmaf(pn0, pn0, q2); q2 = fmaf(pn1, pn1, q2);
        s3 += en0 + en1; q3 = fmaf(en0, en0, q3); q3 = fmaf(en1, en1, q3);
    }
    s4[WPAD + w] = make_float4(Tp, Qp, Te, Qe);        // unscaled (r-units)
    if (blockIdx.x == 0 && threadIdx.x < WPAD)         // zero pads (t<0)
        s4[threadIdx.x] = make_float4(0, 0, 0, 0);

    __shared__ double red[4][8];
    double vv[8] = {s0, s1, s2c, s3, q0, q1, q2, q3};
    const int wid = threadIdx.x >> 6, lane = threadIdx.x & 63;
#pragma unroll
    for (int c = 0; c < 8; ++c) {
        double val = vv[c];
        for (int off = 32; off > 0; off >>= 1) val += __shfl_down(val, off, 64);
        if (lane == 0) red[wid][c] = val;
    }
    __syncthreads();
    if (threadIdx.x < 8) {
        int c = threadIdx.x;
        pp[c * 512 + blockIdx.x] = red[0][c] + red[1][c] + red[2][c] + red[3][c];
    }
}

// ---------------- scan kernel (state r = s/x1) ----------------
#define CL(v) fminf(fmaxf((v), 0.0f), rmax)

#define DRIFT(RV, C, OUT)                                                  \
    {                                                                      \
        float r_  = (RV);                                                  \
        float P_  = fmaf(-r_, r_, 1.0f) * fmaf(-r_, (C).y, (C).x);         \
        float E_  = (r_ * (2.0f - r_)) * fmaf(-(1.0f - r_), (C).w, (C).z); \
        float y_  = r_ * C49;                                              \
        float y2_ = y_ * y_;                                               \
        float u_  = y2_ * y2_;                                             \
        float pl_ = fmaf(u_, fmaf(u_, 1.875f, -2.5f), 4.0f);  /* 16x */    \
        OUT = P_ - E_ - (r_ * u_) * pl_;                                   \
    }

#define CSTEP(C)                                                           \
    {                                                                      \
        float k1_, k2_;                                                    \
        DRIFT(r, C, k1_)                                                   \
        float sm_ = CL(r + k1_);                                           \
        DRIFT(sm_, C, k2_)                                                 \
        r = CL(fmaf(0.5f, k1_ + k2_, r));                                  \
    }

#define CGRP_R(OFF)                                                        \
    CSTEP(c0) c0 = ps4[(OFF) + 8];  CSTEP(c1) c1 = ps4[(OFF) + 9];         \
    CSTEP(c2) c2 = ps4[(OFF) + 10]; CSTEP(c3) c3 = ps4[(OFF) + 11];        \
    CSTEP(c4) c4 = ps4[(OFF) + 12]; CSTEP(c5) c5 = ps4[(OFF) + 13];        \
    CSTEP(c6) c6 = ps4[(OFF) + 14]; CSTEP(c7) c7 = ps4[(OFF) + 15];
#define CGRP_L                                                             \
    CSTEP(c0) CSTEP(c1) CSTEP(c2) CSTEP(c3)                                \
    CSTEP(c4) CSTEP(c5) CSTEP(c6) CSTEP(c7)

// diet tail step v3: 14 VALU (corrections dropped; biases cancel)
#define FSTEP(a, b)                                                        \
    {                                                                      \
        float t1  = fmaf(-r, r, 1.0f);                                     \
        float dp  = (a) * t1;                                              \
        float de  = (r * (2.0f - r)) * (b);                                \
        float r1  = r + (dp - de);                                         \
        float y   = r1 * C49; float y2 = y * y; float u = y2 * y2;         \
        float pl  = fmaf(u, -0.15625f, 0.25f);                             \
        r = r1 - (r1 * u) * pl;                                            \
    }

// full-precision emit step (absolute outputs via x1s at the end)
#define ESTEP(a, b, PS, PC)                                                \
    {                                                                      \
        float tp  = (a) * fmaf((a) * (a), -0.33333334f, 1.0f);             \
        float te  = (b) * fmaf((b) * (b), -0.33333334f, 1.0f);             \
        float e1  = r * tp;                                                \
        float q1v = (1.0f - e1) * fmaf(e1, e1, 1.0f);                      \
        float dp  = (tp * fmaf(-r, r, 1.0f)) * q1v;                        \
        float omr = 1.0f - r;                                              \
        float e2  = te * omr;                                              \
        float q2v = (1.0f - e2) * fmaf(e2, e2, 1.0f);                      \
        float de  = ((r * (2.0f - r)) * te) * q2v;                         \
        float r1  = r + (dp - de);                                         \
        float y   = r1 * C49; float y2 = y * y; float u = y2 * y2;         \
        float pl  = fmaf(u, fmaf(u, 0.1171875f, -0.15625f), 0.25f);        \
        float pcr = (r1 * u) * pl;                                         \
        r = r1 - pcr;                                                      \
        PS = x1s * dp;                                                     \
        PC = x1s * pcr;                                                    \
    }

#define RD(Sb, mm) (*(const float2*)(lbase + ((Sb) ^ ((mm) << 3))))

// consume ring slot + prefetch 4 ahead (crossing into next group via Sn)
#define FQ(RN, mm)                                                         \
    FSTEP(RN.x, RN.y)                                                      \
    RN = ((mm) < 12) ? RD(Sc, (mm) + 4) : RD(Sn, (mm) - 12);

// emit pair (guard m0<12: last needed load at m0=10 -> elements 14,15)
#define EPAIR2(RA, RB, m0)                                                 \
    {                                                                      \
        float psA, pcA, psB, pcB;                                          \
        ESTEP(RA.x, RA.y, psA, pcA)                                        \
        ESTEP(RB.x, RB.y, psB, pcB)                                        \
        if (SIDE) {                                                        \
            *(float4*)(side + 2 * (size_t)(t0 + (m0))) =                   \
                make_float4(psA, pcA, psB, pcB);                           \
        } else {                                                           \
            *(float2*)(out + 6 * (size_t)(t0 + (m0)) + 4)  = make_float2(psA, pcA); \
            *(float2*)(out + 6 * (size_t)(t0 + (m0)) + 10) = make_float2(psB, pcB); \
        }                                                                  \
        sum4 += psA + psB; sq4 = fmaf(psA, psA, sq4); sq4 = fmaf(psB, psB, sq4); \
        sum5 += pcA + pcB; sq5 = fmaf(pcA, pcA, sq5); sq5 = fmaf(pcB, pcB, sq5); \
        if ((m0) < 12) { RA = RD(Se, (m0) + 4); RB = RD(Se, (m0) + 5); }   \
    }

template <bool SIDE>
__global__ __launch_bounds__(256, 2) void scan_kernel(const float4* __restrict__ x4,
                                                      const float* __restrict__ x1p,
                                                      const float4* __restrict__ s4,
                                                      float* __restrict__ out,
                                                      float* __restrict__ side,
                                                      double* __restrict__ sp) {
    __shared__ float2 plane[LDSN];
    __shared__ double red[4][4];

    const float x1s    = x1p[0];
    const float inv_x1 = 1.0f / x1s;
    const float rmax   = 320.0f * inv_x1;
    const int k  = blockIdx.x * 256 + threadIdx.x;     // chunk id
    const int kp = threadIdx.x;                        // chunk offset in block
    const char* lbase = (const char*)plane;

    // ---- stage pre-scaled (a,b)=(pn,en)/x1 into swizzled LDS (coalesced) ----
    {
        const int g0 = 8 * (blockIdx.x * 256) - NTAIL / 2;   // float4 base
        for (int t = threadIdx.x; t < NSTAGE; t += 256) {
            int g4 = g0 + t;
            float4 v = x4[min(max(g4, 0), X4MAX)];
            float a0 = fmaxf(v.x - v.y, 0.0f) * inv_x1;
            float b0 = fmaxf(v.y - v.x, 0.0f) * inv_x1;
            float a1 = fmaxf(v.z - v.w, 0.0f) * inv_x1;
            float b1 = fmaxf(v.w - v.z, 0.0f) * inv_x1;
            if (g4 < 0) { a0 = b0 = a1 = b1 = 0.0f; }  // t<0 -> identity steps
            plane[SWZ(2 * t)]     = make_float2(a0, b0);
            plane[SWZ(2 * t + 1)] = make_float2(a1, b1);
        }
    }

    // ---- coarse phase: windows k-40..k-9 -> padded idx k..k+31 ----
    const float4* ps4 = s4 + k;                        // coalesced across lanes
    float4 c0 = ps4[0], c1 = ps4[1], c2 = ps4[2], c3 = ps4[3],
           c4 = ps4[4], c5 = ps4[5], c6 = ps4[6], c7 = ps4[7];
    float r = 0.0f;
    CGRP_R(0) CGRP_R(8) CGRP_R(16) CGRP_L              // 32 coarse windows

    __syncthreads();                                   // staging visible

    // ---- exact tail: 128 steps, looped 16/iter, 4-deep LDS ring ----
    float2 r0, r1, r2, r3;
    {
        const int S0 = SWZ(16 * kp) << 3;
        r0 = RD(S0, 0); r1 = RD(S0, 1); r2 = RD(S0, 2); r3 = RD(S0, 3);
    }
#pragma unroll 1
    for (int B = 0; B < NTAIL; B += 16) {
        const int W0 = 16 * kp + B;
        const int Sc = SWZ(W0) << 3;
        const int Sn = SWZ(W0 + 16) << 3;
        FQ(r0, 0)  FQ(r1, 1)  FQ(r2, 2)  FQ(r3, 3)
        FQ(r0, 4)  FQ(r1, 5)  FQ(r2, 6)  FQ(r3, 7)
        FQ(r0, 8)  FQ(r1, 9)  FQ(r2, 10) FQ(r3, 11)
        FQ(r0, 12) FQ(r1, 13) FQ(r2, 14) FQ(r3, 15)
    }

    // ---- exact emit: 16 steps (ring holds elements NTAIL..NTAIL+3) ----
    float sum4 = 0, sum5 = 0, sq4 = 0, sq5 = 0;
    const int t0 = 16 * k;
    const int Se = SWZ(16 * kp + NTAIL) << 3;
    EPAIR2(r0, r1, 0)  EPAIR2(r2, r3, 2)
    EPAIR2(r0, r1, 4)  EPAIR2(r2, r3, 6)
    EPAIR2(r0, r1, 8)  EPAIR2(r2, r3, 10)
    EPAIR2(r0, r1, 12) EPAIR2(r2, r3, 14)

    double vv[4] = {sum4, sum5, sq4, sq5};
    const int wid = threadIdx.x >> 6, lane = threadIdx.x & 63;
#pragma unroll
    for (int c = 0; c < 4; ++c) {
        double val = vv[c];
        for (int off = 32; off > 0; off >>= 1) val += __shfl_down(val, off, 64);
        if (lane == 0) red[wid][c] = val;
    }
    __syncthreads();
    if (threadIdx.x < 4) {
        int c = threadIdx.x;
        sp[c * 512 + blockIdx.x] = red[0][c] + red[1][c] + red[2][c] + red[3][c];
    }
}

// ---------------- finalize: reduce partials -> musig ----------------
__global__ __launch_bounds__(256) void finalize_kernel(const double* __restrict__ pp,
                                                       const double* __restrict__ sp,
                                                       float* __restrict__ musig) {
    __shared__ double red[12][4];
    const int t = threadIdx.x, lane = t & 63, wid = t >> 6;
#pragma unroll
    for (int c = 0; c < 8; ++c) {
        double v = pp[c * 512 + t] + pp[c * 512 + 256 + t];
        for (int off = 32; off > 0; off >>= 1) v += __shfl_down(v, off, 64);
        if (lane == 0) red[c][wid] = v;
    }
#pragma unroll
    for (int c = 0; c < 4; ++c) {
        double v = sp[c * 512 + t] + sp[c * 512 + 256 + t];
        for (int off = 32; off > 0; off >>= 1) v += __shfl_down(v, off, 64);
        if (lane == 0) red[8 + c][wid] = v;
    }
    __syncthreads();
    if (t < 6) {
        int si = (t < 4) ? t : (4 + t);
        int qi = (t < 4) ? (4 + t) : (6 + t);
        double sum = red[si][0] + red[si][1] + red[si][2] + red[si][3];
        double sq  = red[qi][0] + red[qi][1] + red[qi][2] + red[qi][3];
        double n = (double)T_TOTAL;
        double mu = sum / n;
        double var = (sq - sum * sum / n) / (n - 1.0);
        musig[t] = (float)mu;
        musig[6 + t] = (float)(1.0 / sqrt(var));
    }
}

// ---------------- normalize ----------------
template <bool SIDE>
__global__ __launch_bounds__(256) void normalize_kernel(const float4* __restrict__ xp4,
                                                        const float4* __restrict__ side4,
                                                        float* __restrict__ out,
                                                        const float* __restrict__ musig) {
    float mu[6], is[6];
#pragma unroll
    for (int c = 0; c < 6; ++c) { mu[c] = musig[c]; is[c] = musig[6 + c]; }

    int idx = blockIdx.x * blockDim.x + threadIdx.x;
    int stride = gridDim.x * blockDim.x;
    for (int p = idx; p < T_TOTAL / 2; p += stride) {
        float4 xv = xp4[p];
        float* o = out + 12 * (size_t)p;
        float4 sv;
        if (SIDE) {
            sv = side4[p];
        } else {
            float2 a = *(const float2*)(o + 4);
            float2 b = *(const float2*)(o + 10);
            sv = make_float4(a.x, a.y, b.x, b.y);
        }
        float pn0 = fmaxf(xv.x - xv.y, 0.0f), en0 = fmaxf(xv.y - xv.x, 0.0f);
        float pn1 = fmaxf(xv.z - xv.w, 0.0f), en1 = fmaxf(xv.w - xv.z, 0.0f);
        f4nt o0 = {(xv.x - mu[0]) * is[0], (xv.y - mu[1]) * is[1],
                   (pn0 - mu[2]) * is[2], (en0 - mu[3]) * is[3]};
        f4nt o1 = {(sv.x - mu[4]) * is[4], (sv.y - mu[5]) * is[5],
                   (xv.z - mu[0]) * is[0], (xv.w - mu[1]) * is[1]};
        f4nt o2 = {(pn1 - mu[2]) * is[2], (en1 - mu[3]) * is[3],
                   (sv.z - mu[4]) * is[4], (sv.w - mu[5]) * is[5]};
        __builtin_nontemporal_store(o0, (f4nt*)(o + 0));
        __builtin_nontemporal_store(o1, (f4nt*)(o + 4));
        __builtin_nontemporal_store(o2, (f4nt*)(o + 8));
    }
}

extern "C" void kernel_launch(void* const* d_in, const int* in_sizes, int n_in,
                              void* d_out, int out_size, void* d_ws, size_t ws_size,
                              hipStream_t stream) {
    const float4* x4 = (const float4*)d_in[0];
    const float* x1 = (const float*)d_in[1];
    float* out = (float*)d_out;
    char* ws = (char*)d_ws;
    double* pp = (double*)(ws + OFF_PP);
    double* sp = (double*)(ws + OFF_SP);
    float* musig = (float*)(ws + OFF_MUSIG);
    float4* s4 = (float4*)(ws + OFF_S4);
    float* side = (float*)(ws + OFF_SIDE);

    const bool use_side = ws_size >= (size_t)OFF_SIDE + (size_t)T_TOTAL * 8;

    prepass_kernel<<<NBLOCKS, THREADS, 0, stream>>>(x4, x1, s4, pp);
    if (use_side) {
        scan_kernel<true><<<NBLOCKS, THREADS, 0, stream>>>(x4, x1, s4, out, side, sp);
        finalize_kernel<<<1, 256, 0, stream>>>(pp, sp, musig);
        normalize_kernel<true><<<2048, 256, 0, stream>>>(x4, (const float4*)side, out, musig);
    } else {
        scan_kernel<false><<<NBLOCKS, THREADS, 0, stream>>>(x4, x1, s4, out, side, sp);
        finalize_kernel<<<1, 256, 0, stream>>>(pp, sp, musig);
        normalize_kernel<false><<<2048, 256, 0, stream>>>(x4, (const float4*)side, out, musig);
    }
}

// Round 16
// 55.086 us; speedup vs baseline: 1.4044x; 1.4044x over previous
//
#include <hip/hip_runtime.h>

// T=2^21 sequential nonlinear storage recurrence + per-column z-score.
// R16 = R15 with normalize reverted to plain float4 stores. R15's A/B showed
// nontemporal stores REGRESSED normalize by ~20us (48B/lane pattern -> partial
// line HBM writes without L2 write-combining). Scan keeps the R14/R15 diet:
//  - tail FSTEP 14 VALU (divisor corrections dropped; biases cancel)
//  - NCOARSE 32, NTAIL 128 (absmax 0.125 measured, thr 0.175)

#define T_TOTAL   (1 << 21)
#define L_CHUNK   16
#define C_CHUNKS  (T_TOTAL / L_CHUNK)        // 131072 chunks == windows
#define NCOARSE   32
#define NTAIL     128
#define WPAD      40                         // NCOARSE + NTAIL/16
#define THREADS   256
#define NBLOCKS   (C_CHUNKS / THREADS)       // 512 -> 2 blocks/CU, 2 waves/SIMD
#define LDSN      4256                       // float2 slots (need 4240)
#define NSTAGE    2120                       // float4s per block window
#define X4MAX     (T_TOTAL / 2 - 1)
#define C49       0.44444445f

// ws layout (bytes)
#define OFF_PP    0                                   // [8][512] double
#define OFF_SP    32768                               // [4][512] double
#define OFF_MUSIG 49152                               // 12 float
#define OFF_S4    49664                               // (WPAD+C) float4
#define OFF_SIDE  (OFF_S4 + (WPAD + C_CHUNKS) * 16)   // T float2 (ps,perc)

#define SWZ(w) ((w) ^ (((w) >> 4) & 31))

// ---------------- pre-pass: per-window sufficient statistics (r-units) ----
__global__ __launch_bounds__(256, 2) void prepass_kernel(const float4* __restrict__ x4,
                                                         const float* __restrict__ x1p,
                                                         float4* __restrict__ s4,
                                                         double* __restrict__ pp) {
    const float x1s    = x1p[0];
    const float inv_x1 = 1.0f / x1s;
    const int w = blockIdx.x * 256 + threadIdx.x;     // window id
    const float4* px = x4 + 8 * (size_t)w;

    float Tp = 0, Qp = 0, Te = 0, Qe = 0;
    float s0 = 0, s1 = 0, s2c = 0, s3 = 0, q0 = 0, q1 = 0, q2 = 0, q3 = 0;
#pragma unroll
    for (int q = 0; q < 8; ++q) {
        float4 v = px[q];
        float pn0 = fmaxf(v.x - v.y, 0.0f), en0 = fmaxf(v.y - v.x, 0.0f);
        float pn1 = fmaxf(v.z - v.w, 0.0f), en1 = fmaxf(v.w - v.z, 0.0f);
        float a0 = pn0 * inv_x1, b0 = en0 * inv_x1;
        float a1 = pn1 * inv_x1, b1 = en1 * inv_x1;
        float tp0 = a0 * fmaf(a0 * a0, -0.33333334f, 1.0f);
        float te0 = b0 * fmaf(b0 * b0, -0.33333334f, 1.0f);
        float tp1 = a1 * fmaf(a1 * a1, -0.33333334f, 1.0f);
        float te1 = b1 * fmaf(b1 * b1, -0.33333334f, 1.0f);
        Tp += tp0 + tp1;  Te += te0 + te1;
        Qp = fmaf(tp0, tp0, Qp); Qp = fmaf(tp1, tp1, Qp);
        Qe = fmaf(te0, te0, Qe); Qe = fmaf(te1, te1, Qe);
        s0 += v.x + v.z; q0 = fmaf(v.x, v.x, q0); q0 = fmaf(v.z, v.z, q0);
        s1 += v.y + v.w; q1 = fmaf(v.y, v.y, q1); q1 = fmaf(v.w, v.w, q1);
        s2c += pn0 + pn1; q2 = fmaf(pn0, pn0, q2); q2 = fmaf(pn1, pn1, q2);
        s3 += en0 + en1; q3 = fmaf(en0, en0, q3); q3 = fmaf(en1, en1, q3);
    }
    s4[WPAD + w] = make_float4(Tp, Qp, Te, Qe);        // unscaled (r-units)
    if (blockIdx.x == 0 && threadIdx.x < WPAD)         // zero pads (t<0)
        s4[threadIdx.x] = make_float4(0, 0, 0, 0);

    __shared__ double red[4][8];
    double vv[8] = {s0, s1, s2c, s3, q0, q1, q2, q3};
    const int wid = threadIdx.x >> 6, lane = threadIdx.x & 63;
#pragma unroll
    for (int c = 0; c < 8; ++c) {
        double val = vv[c];
        for (int off = 32; off > 0; off >>= 1) val += __shfl_down(val, off, 64);
        if (lane == 0) red[wid][c] = val;
    }
    __syncthreads();
    if (threadIdx.x < 8) {
        int c = threadIdx.x;
        pp[c * 512 + blockIdx.x] = red[0][c] + red[1][c] + red[2][c] + red[3][c];
    }
}

// ---------------- scan kernel (state r = s/x1) ----------------
#define CL(v) fminf(fmaxf((v), 0.0f), rmax)

#define DRIFT(RV, C, OUT)                                                  \
    {                                                                      \
        float r_  = (RV);                                                  \
        float P_  = fmaf(-r_, r_, 1.0f) * fmaf(-r_, (C).y, (C).x);         \
        float E_  = (r_ * (2.0f - r_)) * fmaf(-(1.0f - r_), (C).w, (C).z); \
        float y_  = r_ * C49;                                              \
        float y2_ = y_ * y_;                                               \
        float u_  = y2_ * y2_;                                             \
        float pl_ = fmaf(u_, fmaf(u_, 1.875f, -2.5f), 4.0f);  /* 16x */    \
        OUT = P_ - E_ - (r_ * u_) * pl_;                                   \
    }

#define CSTEP(C)                                                           \
    {                                                                      \
        float k1_, k2_;                                                    \
        DRIFT(r, C, k1_)                                                   \
        float sm_ = CL(r + k1_);                                           \
        DRIFT(sm_, C, k2_)                                                 \
        r = CL(fmaf(0.5f, k1_ + k2_, r));                                  \
    }

#define CGRP_R(OFF)                                                        \
    CSTEP(c0) c0 = ps4[(OFF) + 8];  CSTEP(c1) c1 = ps4[(OFF) + 9];         \
    CSTEP(c2) c2 = ps4[(OFF) + 10]; CSTEP(c3) c3 = ps4[(OFF) + 11];        \
    CSTEP(c4) c4 = ps4[(OFF) + 12]; CSTEP(c5) c5 = ps4[(OFF) + 13];        \
    CSTEP(c6) c6 = ps4[(OFF) + 14]; CSTEP(c7) c7 = ps4[(OFF) + 15];
#define CGRP_L                                                             \
    CSTEP(c0) CSTEP(c1) CSTEP(c2) CSTEP(c3)                                \
    CSTEP(c4) CSTEP(c5) CSTEP(c6) CSTEP(c7)

// diet tail step: 14 VALU (corrections dropped; biases cancel)
#define FSTEP(a, b)                                                        \
    {                                                                      \
        float t1  = fmaf(-r, r, 1.0f);                                     \
        float dp  = (a) * t1;                                              \
        float de  = (r * (2.0f - r)) * (b);                                \
        float r1  = r + (dp - de);                                         \
        float y   = r1 * C49; float y2 = y * y; float u = y2 * y2;         \
        float pl  = fmaf(u, -0.15625f, 0.25f);                             \
        r = r1 - (r1 * u) * pl;                                            \
    }

// full-precision emit step (absolute outputs via x1s at the end)
#define ESTEP(a, b, PS, PC)                                                \
    {                                                                      \
        float tp  = (a) * fmaf((a) * (a), -0.33333334f, 1.0f);             \
        float te  = (b) * fmaf((b) * (b), -0.33333334f, 1.0f);             \
        float e1  = r * tp;                                                \
        float q1v = (1.0f - e1) * fmaf(e1, e1, 1.0f);                      \
        float dp  = (tp * fmaf(-r, r, 1.0f)) * q1v;                        \
        float omr = 1.0f - r;                                              \
        float e2  = te * omr;                                              \
        float q2v = (1.0f - e2) * fmaf(e2, e2, 1.0f);                      \
        float de  = ((r * (2.0f - r)) * te) * q2v;                         \
        float r1  = r + (dp - de);                                         \
        float y   = r1 * C49; float y2 = y * y; float u = y2 * y2;         \
        float pl  = fmaf(u, fmaf(u, 0.1171875f, -0.15625f), 0.25f);        \
        float pcr = (r1 * u) * pl;                                         \
        r = r1 - pcr;                                                      \
        PS = x1s * dp;                                                     \
        PC = x1s * pcr;                                                    \
    }

#define RD(Sb, mm) (*(const float2*)(lbase + ((Sb) ^ ((mm) << 3))))

// consume ring slot + prefetch 4 ahead (crossing into next group via Sn)
#define FQ(RN, mm)                                                         \
    FSTEP(RN.x, RN.y)                                                      \
    RN = ((mm) < 12) ? RD(Sc, (mm) + 4) : RD(Sn, (mm) - 12);

// emit pair (guard m0<12: last needed load at m0=10 -> elements 14,15)
#define EPAIR2(RA, RB, m0)                                                 \
    {                                                                      \
        float psA, pcA, psB, pcB;                                          \
        ESTEP(RA.x, RA.y, psA, pcA)                                        \
        ESTEP(RB.x, RB.y, psB, pcB)                                        \
        if (SIDE) {                                                        \
            *(float4*)(side + 2 * (size_t)(t0 + (m0))) =                   \
                make_float4(psA, pcA, psB, pcB);                           \
        } else {                                                           \
            *(float2*)(out + 6 * (size_t)(t0 + (m0)) + 4)  = make_float2(psA, pcA); \
            *(float2*)(out + 6 * (size_t)(t0 + (m0)) + 10) = make_float2(psB, pcB); \
        }                                                                  \
        sum4 += psA + psB; sq4 = fmaf(psA, psA, sq4); sq4 = fmaf(psB, psB, sq4); \
        sum5 += pcA + pcB; sq5 = fmaf(pcA, pcA, sq5); sq5 = fmaf(pcB, pcB, sq5); \
        if ((m0) < 12) { RA = RD(Se, (m0) + 4); RB = RD(Se, (m0) + 5); }   \
    }

template <bool SIDE>
__global__ __launch_bounds__(256, 2) void scan_kernel(const float4* __restrict__ x4,
                                                      const float* __restrict__ x1p,
                                                      const float4* __restrict__ s4,
                                                      float* __restrict__ out,
                                                      float* __restrict__ side,
                                                      double* __restrict__ sp) {
    __shared__ float2 plane[LDSN];
    __shared__ double red[4][4];

    const float x1s    = x1p[0];
    const float inv_x1 = 1.0f / x1s;
    const float rmax   = 320.0f * inv_x1;
    const int k  = blockIdx.x * 256 + threadIdx.x;     // chunk id
    const int kp = threadIdx.x;                        // chunk offset in block
    const char* lbase = (const char*)plane;

    // ---- stage pre-scaled (a,b)=(pn,en)/x1 into swizzled LDS (coalesced) ----
    {
        const int g0 = 8 * (blockIdx.x * 256) - NTAIL / 2;   // float4 base
        for (int t = threadIdx.x; t < NSTAGE; t += 256) {
            int g4 = g0 + t;
            float4 v = x4[min(max(g4, 0), X4MAX)];
            float a0 = fmaxf(v.x - v.y, 0.0f) * inv_x1;
            float b0 = fmaxf(v.y - v.x, 0.0f) * inv_x1;
            float a1 = fmaxf(v.z - v.w, 0.0f) * inv_x1;
            float b1 = fmaxf(v.w - v.z, 0.0f) * inv_x1;
            if (g4 < 0) { a0 = b0 = a1 = b1 = 0.0f; }  // t<0 -> identity steps
            plane[SWZ(2 * t)]     = make_float2(a0, b0);
            plane[SWZ(2 * t + 1)] = make_float2(a1, b1);
        }
    }

    // ---- coarse phase: windows k-40..k-9 -> padded idx k..k+31 ----
    const float4* ps4 = s4 + k;                        // coalesced across lanes
    float4 c0 = ps4[0], c1 = ps4[1], c2 = ps4[2], c3 = ps4[3],
           c4 = ps4[4], c5 = ps4[5], c6 = ps4[6], c7 = ps4[7];
    float r = 0.0f;
    CGRP_R(0) CGRP_R(8) CGRP_R(16) CGRP_L              // 32 coarse windows

    __syncthreads();                                   // staging visible

    // ---- exact tail: 128 steps, looped 16/iter, 4-deep LDS ring ----
    float2 r0, r1, r2, r3;
    {
        const int S0 = SWZ(16 * kp) << 3;
        r0 = RD(S0, 0); r1 = RD(S0, 1); r2 = RD(S0, 2); r3 = RD(S0, 3);
    }
#pragma unroll 1
    for (int B = 0; B < NTAIL; B += 16) {
        const int W0 = 16 * kp + B;
        const int Sc = SWZ(W0) << 3;
        const int Sn = SWZ(W0 + 16) << 3;
        FQ(r0, 0)  FQ(r1, 1)  FQ(r2, 2)  FQ(r3, 3)
        FQ(r0, 4)  FQ(r1, 5)  FQ(r2, 6)  FQ(r3, 7)
        FQ(r0, 8)  FQ(r1, 9)  FQ(r2, 10) FQ(r3, 11)
        FQ(r0, 12) FQ(r1, 13) FQ(r2, 14) FQ(r3, 15)
    }

    // ---- exact emit: 16 steps (ring holds elements NTAIL..NTAIL+3) ----
    float sum4 = 0, sum5 = 0, sq4 = 0, sq5 = 0;
    const int t0 = 16 * k;
    const int Se = SWZ(16 * kp + NTAIL) << 3;
    EPAIR2(r0, r1, 0)  EPAIR2(r2, r3, 2)
    EPAIR2(r0, r1, 4)  EPAIR2(r2, r3, 6)
    EPAIR2(r0, r1, 8)  EPAIR2(r2, r3, 10)
    EPAIR2(r0, r1, 12) EPAIR2(r2, r3, 14)

    double vv[4] = {sum4, sum5, sq4, sq5};
    const int wid = threadIdx.x >> 6, lane = threadIdx.x & 63;
#pragma unroll
    for (int c = 0; c < 4; ++c) {
        double val = vv[c];
        for (int off = 32; off > 0; off >>= 1) val += __shfl_down(val, off, 64);
        if (lane == 0) red[wid][c] = val;
    }
    __syncthreads();
    if (threadIdx.x < 4) {
        int c = threadIdx.x;
        sp[c * 512 + blockIdx.x] = red[0][c] + red[1][c] + red[2][c] + red[3][c];
    }
}

// ---------------- finalize: reduce partials -> musig ----------------
__global__ __launch_bounds__(256) void finalize_kernel(const double* __restrict__ pp,
                                                       const double* __restrict__ sp,
                                                       float* __restrict__ musig) {
    __shared__ double red[12][4];
    const int t = threadIdx.x, lane = t & 63, wid = t >> 6;
#pragma unroll
    for (int c = 0; c < 8; ++c) {
        double v = pp[c * 512 + t] + pp[c * 512 + 256 + t];
        for (int off = 32; off > 0; off >>= 1) v += __shfl_down(v, off, 64);
        if (lane == 0) red[c][wid] = v;
    }
#pragma unroll
    for (int c = 0; c < 4; ++c) {
        double v = sp[c * 512 + t] + sp[c * 512 + 256 + t];
        for (int off = 32; off > 0; off >>= 1) v += __shfl_down(v, off, 64);
        if (lane == 0) red[8 + c][wid] = v;
    }
    __syncthreads();
    if (t < 6) {
        int si = (t < 4) ? t : (4 + t);
        int qi = (t < 4) ? (4 + t) : (6 + t);
        double sum = red[si][0] + red[si][1] + red[si][2] + red[si][3];
        double sq  = red[qi][0] + red[qi][1] + red[qi][2] + red[qi][3];
        double n = (double)T_TOTAL;
        double mu = sum / n;
        double var = (sq - sum * sum / n) / (n - 1.0);
        musig[t] = (float)mu;
        musig[6 + t] = (float)(1.0 / sqrt(var));
    }
}

// ---------------- normalize (plain float4 stores) ----------------
template <bool SIDE>
__global__ __launch_bounds__(256) void normalize_kernel(const float4* __restrict__ xp4,
                                                        const float4* __restrict__ side4,
                                                        float* __restrict__ out,
                                                        const float* __restrict__ musig) {
    float mu[6], is[6];
#pragma unroll
    for (int c = 0; c < 6; ++c) { mu[c] = musig[c]; is[c] = musig[6 + c]; }

    int idx = blockIdx.x * blockDim.x + threadIdx.x;
    int stride = gridDim.x * blockDim.x;
    for (int p = idx; p < T_TOTAL / 2; p += stride) {
        float4 xv = xp4[p];
        float* o = out + 12 * (size_t)p;
        float4 sv;
        if (SIDE) {
            sv = side4[p];
        } else {
            float2 a = *(const float2*)(o + 4);
            float2 b = *(const float2*)(o + 10);
            sv = make_float4(a.x, a.y, b.x, b.y);
        }
        float pn0 = fmaxf(xv.x - xv.y, 0.0f), en0 = fmaxf(xv.y - xv.x, 0.0f);
        float pn1 = fmaxf(xv.z - xv.w, 0.0f), en1 = fmaxf(xv.w - xv.z, 0.0f);
        float4 o0 = {(xv.x - mu[0]) * is[0], (xv.y - mu[1]) * is[1],
                     (pn0 - mu[2]) * is[2], (en0 - mu[3]) * is[3]};
        float4 o1 = {(sv.x - mu[4]) * is[4], (sv.y - mu[5]) * is[5],
                     (xv.z - mu[0]) * is[0], (xv.w - mu[1]) * is[1]};
        float4 o2 = {(pn1 - mu[2]) * is[2], (en1 - mu[3]) * is[3],
                     (sv.z - mu[4]) * is[4], (sv.w - mu[5]) * is[5]};
        *(float4*)(o + 0) = o0;
        *(float4*)(o + 4) = o1;
        *(float4*)(o + 8) = o2;
    }
}

extern "C" void kernel_launch(void* const* d_in, const int* in_sizes, int n_in,
                              void* d_out, int out_size, void* d_ws, size_t ws_size,
                              hipStream_t stream) {
    const float4* x4 = (const float4*)d_in[0];
    const float* x1 = (const float*)d_in[1];
    float* out = (float*)d_out;
    char* ws = (char*)d_ws;
    double* pp = (double*)(ws + OFF_PP);
    double* sp = (double*)(ws + OFF_SP);
    float* musig = (float*)(ws + OFF_MUSIG);
    float4* s4 = (float4*)(ws + OFF_S4);
    float* side = (float*)(ws + OFF_SIDE);

    const bool use_side = ws_size >= (size_t)OFF_SIDE + (size_t)T_TOTAL * 8;

    prepass_kernel<<<NBLOCKS, THREADS, 0, stream>>>(x4, x1, s4, pp);
    if (use_side) {
        scan_kernel<true><<<NBLOCKS, THREADS, 0, stream>>>(x4, x1, s4, out, side, sp);
        finalize_kernel<<<1, 256, 0, stream>>>(pp, sp, musig);
        normalize_kernel<true><<<2048, 256, 0, stream>>>(x4, (const float4*)side, out, musig);
    } else {
        scan_kernel<false><<<NBLOCKS, THREADS, 0, stream>>>(x4, x1, s4, out, side, sp);
        finalize_kernel<<<1, 256, 0, stream>>>(pp, sp, musig);
        normalize_kernel<false><<<2048, 256, 0, stream>>>(x4, (const float4*)side, out, musig);
    }
}

// Round 18
// 52.860 us; speedup vs baseline: 1.4636x; 1.0421x over previous
//
#include <hip/hip_runtime.h>

// T=2^21 sequential nonlinear storage recurrence + per-column z-score.
// R18 = R17 with macro-hygiene fix (FSTEP/ESTEP locals renamed *_ ; R17's
// local `float r1` captured the ring register r1 in FQ(r1,..)). Content:
//  - tail drift quadratic: dp-de = a - 2b*r - (a-b)*r^2; LDS stages (a,2b);
//    FSTEP 14->11 VALU
//  - coarse drift cubic: P-E = c0+c1*r+c2*r^2+c3*r^3; prepass stores coeffs
//  - emit divisor corrections first-order only (rel err <= 7e-4)
// Skeleton identical to R16 (best: 55.1us, absmax 0.125).

#define T_TOTAL   (1 << 21)
#define L_CHUNK   16
#define C_CHUNKS  (T_TOTAL / L_CHUNK)        // 131072 chunks == windows
#define NCOARSE   32
#define NTAIL     128
#define WPAD      40                         // NCOARSE + NTAIL/16
#define THREADS   256
#define NBLOCKS   (C_CHUNKS / THREADS)       // 512 -> 2 blocks/CU, 2 waves/SIMD
#define LDSN      4256                       // float2 slots (need 4240)
#define NSTAGE    2120                       // float4s per block window
#define X4MAX     (T_TOTAL / 2 - 1)
#define C49       0.44444445f

// ws layout (bytes)
#define OFF_PP    0                                   // [8][512] double
#define OFF_SP    32768                               // [4][512] double
#define OFF_MUSIG 49152                               // 12 float
#define OFF_S4    49664                               // (WPAD+C) float4
#define OFF_SIDE  (OFF_S4 + (WPAD + C_CHUNKS) * 16)   // T float2 (ps,perc)

#define SWZ(w) ((w) ^ (((w) >> 4) & 31))

// ---------------- pre-pass: per-window drift-cubic coefficients ----------
__global__ __launch_bounds__(256, 2) void prepass_kernel(const float4* __restrict__ x4,
                                                         const float* __restrict__ x1p,
                                                         float4* __restrict__ s4,
                                                         double* __restrict__ pp) {
    const float x1s    = x1p[0];
    const float inv_x1 = 1.0f / x1s;
    const int w = blockIdx.x * 256 + threadIdx.x;     // window id
    const float4* px = x4 + 8 * (size_t)w;

    float Tp = 0, Qp = 0, Te = 0, Qe = 0;
    float s0 = 0, s1 = 0, s2c = 0, s3 = 0, q0 = 0, q1 = 0, q2 = 0, q3 = 0;
#pragma unroll
    for (int q = 0; q < 8; ++q) {
        float4 v = px[q];
        float pn0 = fmaxf(v.x - v.y, 0.0f), en0 = fmaxf(v.y - v.x, 0.0f);
        float pn1 = fmaxf(v.z - v.w, 0.0f), en1 = fmaxf(v.w - v.z, 0.0f);
        float a0 = pn0 * inv_x1, b0 = en0 * inv_x1;
        float a1 = pn1 * inv_x1, b1 = en1 * inv_x1;
        float tp0 = a0 * fmaf(a0 * a0, -0.33333334f, 1.0f);
        float te0 = b0 * fmaf(b0 * b0, -0.33333334f, 1.0f);
        float tp1 = a1 * fmaf(a1 * a1, -0.33333334f, 1.0f);
        float te1 = b1 * fmaf(b1 * b1, -0.33333334f, 1.0f);
        Tp += tp0 + tp1;  Te += te0 + te1;
        Qp = fmaf(tp0, tp0, Qp); Qp = fmaf(tp1, tp1, Qp);
        Qe = fmaf(te0, te0, Qe); Qe = fmaf(te1, te1, Qe);
        s0 += v.x + v.z; q0 = fmaf(v.x, v.x, q0); q0 = fmaf(v.z, v.z, q0);
        s1 += v.y + v.w; q1 = fmaf(v.y, v.y, q1); q1 = fmaf(v.w, v.w, q1);
        s2c += pn0 + pn1; q2 = fmaf(pn0, pn0, q2); q2 = fmaf(pn1, pn1, q2);
        s3 += en0 + en1; q3 = fmaf(en0, en0, q3); q3 = fmaf(en1, en1, q3);
    }
    // cubic coeffs of P-E in r: c0 + c1 r + c2 r^2 + c3 r^3
    float cc0 = Tp;
    float cc1 = 2.0f * (Qe - Te) - Qp;
    float cc2 = Te - Tp - 3.0f * Qe;
    float cc3 = Qp + Qe;
    s4[WPAD + w] = make_float4(cc0, cc1, cc2, cc3);
    if (blockIdx.x == 0 && threadIdx.x < WPAD)         // zero pads (t<0)
        s4[threadIdx.x] = make_float4(0, 0, 0, 0);

    __shared__ double red[4][8];
    double vv[8] = {s0, s1, s2c, s3, q0, q1, q2, q3};
    const int wid = threadIdx.x >> 6, lane = threadIdx.x & 63;
#pragma unroll
    for (int c = 0; c < 8; ++c) {
        double val = vv[c];
        for (int off = 32; off > 0; off >>= 1) val += __shfl_down(val, off, 64);
        if (lane == 0) red[wid][c] = val;
    }
    __syncthreads();
    if (threadIdx.x < 8) {
        int c = threadIdx.x;
        pp[c * 512 + blockIdx.x] = red[0][c] + red[1][c] + red[2][c] + red[3][c];
    }
}

// ---------------- scan kernel (state r = s/x1) ----------------
#define CL(v) fminf(fmaxf((v), 0.0f), rmax)

// window drift: cubic + 16x perc (3-term)
#define DRIFT(RV, C, OUT)                                                  \
    {                                                                      \
        float rr_ = (RV);                                                  \
        float d_ = fmaf(rr_, fmaf(rr_, fmaf(rr_, (C).w, (C).z), (C).y), (C).x); \
        float y_  = rr_ * C49;                                             \
        float y2_ = y_ * y_;                                               \
        float u_  = y2_ * y2_;                                             \
        float pl_ = fmaf(u_, fmaf(u_, 1.875f, -2.5f), 4.0f);               \
        OUT = d_ - (rr_ * u_) * pl_;                                       \
    }

#define CSTEP(C)                                                           \
    {                                                                      \
        float k1_, k2_;                                                    \
        DRIFT(r, C, k1_)                                                   \
        float sm_ = CL(r + k1_);                                           \
        DRIFT(sm_, C, k2_)                                                 \
        r = CL(fmaf(0.5f, k1_ + k2_, r));                                  \
    }

#define CGRP_R(OFF)                                                        \
    CSTEP(c0) c0 = ps4[(OFF) + 8];  CSTEP(c1) c1 = ps4[(OFF) + 9];         \
    CSTEP(c2) c2 = ps4[(OFF) + 10]; CSTEP(c3) c3 = ps4[(OFF) + 11];        \
    CSTEP(c4) c4 = ps4[(OFF) + 12]; CSTEP(c5) c5 = ps4[(OFF) + 13];        \
    CSTEP(c6) c6 = ps4[(OFF) + 14]; CSTEP(c7) c7 = ps4[(OFF) + 15];
#define CGRP_L                                                             \
    CSTEP(c0) CSTEP(c1) CSTEP(c2) CSTEP(c3)                                \
    CSTEP(c4) CSTEP(c5) CSTEP(c6) CSTEP(c7)

// diet tail step (quadratic drift): inputs a, b2=2b; 11 VALU
#define FSTEP(a, b2)                                                       \
    {                                                                      \
        float m_  = fmaf(-0.5f, (b2), (a));            /* a-b */           \
        float rn_ = r + fmaf(r, fmaf(r, -m_, -(b2)), (a));                 \
        float y_  = rn_ * C49; float y2_ = y_ * y_; float u_ = y2_ * y2_;  \
        float pl_ = fmaf(u_, -0.15625f, 0.25f);                            \
        r = rn_ - (rn_ * u_) * pl_;                                        \
    }

// emit step: tanh 2-term, divisor corrections first-order, full perc poly
#define ESTEP(a, b2, PS, PC)                                               \
    {                                                                      \
        float b_   = 0.5f * (b2);                                          \
        float tp_  = (a) * fmaf((a) * (a), -0.33333334f, 1.0f);            \
        float te_  = b_ * fmaf(b_ * b_, -0.33333334f, 1.0f);               \
        float q1_  = fmaf(-r, tp_, 1.0f);              /* 1-e1 */          \
        float dp_  = (tp_ * fmaf(-r, r, 1.0f)) * q1_;                      \
        float omr_ = 1.0f - r;                                             \
        float q2_  = fmaf(-te_, omr_, 1.0f);           /* 1-e2 */          \
        float de_  = ((r * (2.0f - r)) * te_) * q2_;                       \
        float rn_  = r + (dp_ - de_);                                      \
        float y_   = rn_ * C49; float y2_ = y_ * y_; float u_ = y2_ * y2_; \
        float pl_  = fmaf(u_, fmaf(u_, 0.1171875f, -0.15625f), 0.25f);     \
        float pcr_ = (rn_ * u_) * pl_;                                     \
        r = rn_ - pcr_;                                                    \
        PS = x1s * dp_;                                                    \
        PC = x1s * pcr_;                                                   \
    }

#define RD(Sb, mm) (*(const float2*)(lbase + ((Sb) ^ ((mm) << 3))))

// consume ring slot + prefetch 4 ahead (crossing into next group via Sn)
#define FQ(RN, mm)                                                         \
    FSTEP(RN.x, RN.y)                                                      \
    RN = ((mm) < 12) ? RD(Sc, (mm) + 4) : RD(Sn, (mm) - 12);

// emit pair (guard m0<12: last needed load at m0=10 -> elements 14,15)
#define EPAIR2(RA, RB, m0)                                                 \
    {                                                                      \
        float psA, pcA, psB, pcB;                                          \
        ESTEP(RA.x, RA.y, psA, pcA)                                        \
        ESTEP(RB.x, RB.y, psB, pcB)                                        \
        if (SIDE) {                                                        \
            *(float4*)(side + 2 * (size_t)(t0 + (m0))) =                   \
                make_float4(psA, pcA, psB, pcB);                           \
        } else {                                                           \
            *(float2*)(out + 6 * (size_t)(t0 + (m0)) + 4)  = make_float2(psA, pcA); \
            *(float2*)(out + 6 * (size_t)(t0 + (m0)) + 10) = make_float2(psB, pcB); \
        }                                                                  \
        sum4 += psA + psB; sq4 = fmaf(psA, psA, sq4); sq4 = fmaf(psB, psB, sq4); \
        sum5 += pcA + pcB; sq5 = fmaf(pcA, pcA, sq5); sq5 = fmaf(pcB, pcB, sq5); \
        if ((m0) < 12) { RA = RD(Se, (m0) + 4); RB = RD(Se, (m0) + 5); }   \
    }

template <bool SIDE>
__global__ __launch_bounds__(256, 2) void scan_kernel(const float4* __restrict__ x4,
                                                      const float* __restrict__ x1p,
                                                      const float4* __restrict__ s4,
                                                      float* __restrict__ out,
                                                      float* __restrict__ side,
                                                      double* __restrict__ sp) {
    __shared__ float2 plane[LDSN];
    __shared__ double red[4][4];

    const float x1s    = x1p[0];
    const float inv_x1 = 1.0f / x1s;
    const float inv2x  = 2.0f * inv_x1;
    const float rmax   = 320.0f * inv_x1;
    const int k  = blockIdx.x * 256 + threadIdx.x;     // chunk id
    const int kp = threadIdx.x;                        // chunk offset in block
    const char* lbase = (const char*)plane;

    // ---- stage (a, 2b) = (pn/x1, 2*en/x1) into swizzled LDS (coalesced) ----
    {
        const int g0 = 8 * (blockIdx.x * 256) - NTAIL / 2;   // float4 base
        for (int t = threadIdx.x; t < NSTAGE; t += 256) {
            int g4 = g0 + t;
            float4 v = x4[min(max(g4, 0), X4MAX)];
            float a0 = fmaxf(v.x - v.y, 0.0f) * inv_x1;
            float b0 = fmaxf(v.y - v.x, 0.0f) * inv2x;
            float a1 = fmaxf(v.z - v.w, 0.0f) * inv_x1;
            float b1 = fmaxf(v.w - v.z, 0.0f) * inv2x;
            if (g4 < 0) { a0 = b0 = a1 = b1 = 0.0f; }  // t<0 -> identity steps
            plane[SWZ(2 * t)]     = make_float2(a0, b0);
            plane[SWZ(2 * t + 1)] = make_float2(a1, b1);
        }
    }

    // ---- coarse phase: windows k-40..k-9 -> padded idx k..k+31 ----
    const float4* ps4 = s4 + k;                        // coalesced across lanes
    float4 c0 = ps4[0], c1 = ps4[1], c2 = ps4[2], c3 = ps4[3],
           c4 = ps4[4], c5 = ps4[5], c6 = ps4[6], c7 = ps4[7];
    float r = 0.0f;
    CGRP_R(0) CGRP_R(8) CGRP_R(16) CGRP_L              // 32 coarse windows

    __syncthreads();                                   // staging visible

    // ---- exact tail: 128 steps, looped 16/iter, 4-deep LDS ring ----
    float2 r0, r1, r2, r3;
    {
        const int S0 = SWZ(16 * kp) << 3;
        r0 = RD(S0, 0); r1 = RD(S0, 1); r2 = RD(S0, 2); r3 = RD(S0, 3);
    }
#pragma unroll 1
    for (int B = 0; B < NTAIL; B += 16) {
        const int W0 = 16 * kp + B;
        const int Sc = SWZ(W0) << 3;
        const int Sn = SWZ(W0 + 16) << 3;
        FQ(r0, 0)  FQ(r1, 1)  FQ(r2, 2)  FQ(r3, 3)
        FQ(r0, 4)  FQ(r1, 5)  FQ(r2, 6)  FQ(r3, 7)
        FQ(r0, 8)  FQ(r1, 9)  FQ(r2, 10) FQ(r3, 11)
        FQ(r0, 12) FQ(r1, 13) FQ(r2, 14) FQ(r3, 15)
    }

    // ---- exact emit: 16 steps (ring holds elements NTAIL..NTAIL+3) ----
    float sum4 = 0, sum5 = 0, sq4 = 0, sq5 = 0;
    const int t0 = 16 * k;
    const int Se = SWZ(16 * kp + NTAIL) << 3;
    EPAIR2(r0, r1, 0)  EPAIR2(r2, r3, 2)
    EPAIR2(r0, r1, 4)  EPAIR2(r2, r3, 6)
    EPAIR2(r0, r1, 8)  EPAIR2(r2, r3, 10)
    EPAIR2(r0, r1, 12) EPAIR2(r2, r3, 14)

    double vv[4] = {sum4, sum5, sq4, sq5};
    const int wid = threadIdx.x >> 6, lane = threadIdx.x & 63;
#pragma unroll
    for (int c = 0; c < 4; ++c) {
        double val = vv[c];
        for (int off = 32; off > 0; off >>= 1) val += __shfl_down(val, off, 64);
        if (lane == 0) red[wid][c] = val;
    }
    __syncthreads();
    if (threadIdx.x < 4) {
        int c = threadIdx.x;
        sp[c * 512 + blockIdx.x] = red[0][c] + red[1][c] + red[2][c] + red[3][c];
    }
}

// ---------------- finalize: reduce partials -> musig ----------------
__global__ __launch_bounds__(256) void finalize_kernel(const double* __restrict__ pp,
                                                       const double* __restrict__ sp,
                                                       float* __restrict__ musig) {
    __shared__ double red[12][4];
    const int t = threadIdx.x, lane = t & 63, wid = t >> 6;
#pragma unroll
    for (int c = 0; c < 8; ++c) {
        double v = pp[c * 512 + t] + pp[c * 512 + 256 + t];
        for (int off = 32; off > 0; off >>= 1) v += __shfl_down(v, off, 64);
        if (lane == 0) red[c][wid] = v;
    }
#pragma unroll
    for (int c = 0; c < 4; ++c) {
        double v = sp[c * 512 + t] + sp[c * 512 + 256 + t];
        for (int off = 32; off > 0; off >>= 1) v += __shfl_down(v, off, 64);
        if (lane == 0) red[8 + c][wid] = v;
    }
    __syncthreads();
    if (t < 6) {
        int si = (t < 4) ? t : (4 + t);
        int qi = (t < 4) ? (4 + t) : (6 + t);
        double sum = red[si][0] + red[si][1] + red[si][2] + red[si][3];
        double sq  = red[qi][0] + red[qi][1] + red[qi][2] + red[qi][3];
        double n = (double)T_TOTAL;
        double mu = sum / n;
        double var = (sq - sum * sum / n) / (n - 1.0);
        musig[t] = (float)mu;
        musig[6 + t] = (float)(1.0 / sqrt(var));
    }
}

// ---------------- normalize (plain float4 stores) ----------------
template <bool SIDE>
__global__ __launch_bounds__(256) void normalize_kernel(const float4* __restrict__ xp4,
                                                        const float4* __restrict__ side4,
                                                        float* __restrict__ out,
                                                        const float* __restrict__ musig) {
    float mu[6], is[6];
#pragma unroll
    for (int c = 0; c < 6; ++c) { mu[c] = musig[c]; is[c] = musig[6 + c]; }

    int idx = blockIdx.x * blockDim.x + threadIdx.x;
    int stride = gridDim.x * blockDim.x;
    for (int p = idx; p < T_TOTAL / 2; p += stride) {
        float4 xv = xp4[p];
        float* o = out + 12 * (size_t)p;
        float4 sv;
        if (SIDE) {
            sv = side4[p];
        } else {
            float2 a = *(const float2*)(o + 4);
            float2 b = *(const float2*)(o + 10);
            sv = make_float4(a.x, a.y, b.x, b.y);
        }
        float pn0 = fmaxf(xv.x - xv.y, 0.0f), en0 = fmaxf(xv.y - xv.x, 0.0f);
        float pn1 = fmaxf(xv.z - xv.w, 0.0f), en1 = fmaxf(xv.w - xv.z, 0.0f);
        float4 o0 = {(xv.x - mu[0]) * is[0], (xv.y - mu[1]) * is[1],
                     (pn0 - mu[2]) * is[2], (en0 - mu[3]) * is[3]};
        float4 o1 = {(sv.x - mu[4]) * is[4], (sv.y - mu[5]) * is[5],
                     (xv.z - mu[0]) * is[0], (xv.w - mu[1]) * is[1]};
        float4 o2 = {(pn1 - mu[2]) * is[2], (en1 - mu[3]) * is[3],
                     (sv.z - mu[4]) * is[4], (sv.w - mu[5]) * is[5]};
        *(float4*)(o + 0) = o0;
        *(float4*)(o + 4) = o1;
        *(float4*)(o + 8) = o2;
    }
}

extern "C" void kernel_launch(void* const* d_in, const int* in_sizes, int n_in,
                              void* d_out, int out_size, void* d_ws, size_t ws_size,
                              hipStream_t stream) {
    const float4* x4 = (const float4*)d_in[0];
    const float* x1 = (const float*)d_in[1];
    float* out = (float*)d_out;
    char* ws = (char*)d_ws;
    double* pp = (double*)(ws + OFF_PP);
    double* sp = (double*)(ws + OFF_SP);
    float* musig = (float*)(ws + OFF_MUSIG);
    float4* s4 = (float4*)(ws + OFF_S4);
    float* side = (float*)(ws + OFF_SIDE);

    const bool use_side = ws_size >= (size_t)OFF_SIDE + (size_t)T_TOTAL * 8;

    prepass_kernel<<<NBLOCKS, THREADS, 0, stream>>>(x4, x1, s4, pp);
    if (use_side) {
        scan_kernel<true><<<NBLOCKS, THREADS, 0, stream>>>(x4, x1, s4, out, side, sp);
        finalize_kernel<<<1, 256, 0, stream>>>(pp, sp, musig);
        normalize_kernel<true><<<2048, 256, 0, stream>>>(x4, (const float4*)side, out, musig);
    } else {
        scan_kernel<false><<<NBLOCKS, THREADS, 0, stream>>>(x4, x1, s4, out, side, sp);
        finalize_kernel<<<1, 256, 0, stream>>>(pp, sp, musig);
        normalize_kernel<false><<<2048, 256, 0, stream>>>(x4, (const float4*)side, out, musig);
    }
}

// Round 19
// 48.962 us; speedup vs baseline: 1.5801x; 1.0796x over previous
//
#include <hip/hip_runtime.h>

// T=2^21 sequential nonlinear storage recurrence + per-column z-score.
// R19 = R18 with the prepass FUSED into the scan: block stages elements
// [16k0-640, 16k0+4096+16) as (a,2b) in swizzled LDS, computes its 287
// per-window drift-cubic coeffs in LDS (linear-tanh window sums, rel err
// 1.6e-5 << coarse bias), and cols0-3 stats during staging (each block owns
// its 4096 emit elements exactly once). 3 dispatches (was 4); removes the
// duplicate 16MB x read and the s4 global round-trip.

#define T_TOTAL   (1 << 21)
#define C_CHUNKS  (T_TOTAL / 16)             // 131072
#define NCOARSE   32
#define NTAIL     128
#define THREADS   256
#define NBLOCKS   (C_CHUNKS / THREADS)       // 512 -> 2 blocks/CU
#define NSTAGE4   2376                       // float4s staged per block
#define LDSN      4768                       // float2 slots (need 4752)
#define NWIN      287                        // windows per block (coarse range)
#define X4MAX     (T_TOTAL / 2 - 1)
#define C49       0.44444445f

// ws layout (bytes)
#define OFF_SP    0                                   // [12][512] double
#define OFF_MUSIG 49152                               // 12 float
#define OFF_SIDE  49664                               // T float2 (ps,perc)

#define SWZ(w) ((w) ^ (((w) >> 4) & 31))
#define RD(Sb, mm) (*(const float2*)(lbase + ((Sb) ^ ((mm) << 3))))

#define CL(v) fminf(fmaxf((v), 0.0f), rmax)

// window drift: cubic + 16x perc (3-term)
#define DRIFT(RV, C, OUT)                                                  \
    {                                                                      \
        float rr_ = (RV);                                                  \
        float d_ = fmaf(rr_, fmaf(rr_, fmaf(rr_, (C).w, (C).z), (C).y), (C).x); \
        float y_  = rr_ * C49;                                             \
        float y2_ = y_ * y_;                                               \
        float u_  = y2_ * y2_;                                             \
        float pl_ = fmaf(u_, fmaf(u_, 1.875f, -2.5f), 4.0f);               \
        OUT = d_ - (rr_ * u_) * pl_;                                       \
    }

#define CSTEP(C)                                                           \
    {                                                                      \
        float k1_, k2_;                                                    \
        DRIFT(r, C, k1_)                                                   \
        float sm_ = CL(r + k1_);                                           \
        DRIFT(sm_, C, k2_)                                                 \
        r = CL(fmaf(0.5f, k1_ + k2_, r));                                  \
    }

#define WLD(j) make_float4(cA[kp + (j)], cB[kp + (j)], cC[kp + (j)], cD[kp + (j)])

#define CGRP_R(OFF)                                                        \
    CSTEP(c0) c0 = WLD((OFF) + 8);  CSTEP(c1) c1 = WLD((OFF) + 9);         \
    CSTEP(c2) c2 = WLD((OFF) + 10); CSTEP(c3) c3 = WLD((OFF) + 11);        \
    CSTEP(c4) c4 = WLD((OFF) + 12); CSTEP(c5) c5 = WLD((OFF) + 13);        \
    CSTEP(c6) c6 = WLD((OFF) + 14); CSTEP(c7) c7 = WLD((OFF) + 15);
#define CGRP_L                                                             \
    CSTEP(c0) CSTEP(c1) CSTEP(c2) CSTEP(c3)                                \
    CSTEP(c4) CSTEP(c5) CSTEP(c6) CSTEP(c7)

// diet tail step (quadratic drift): inputs a, b2=2b; 11 VALU
#define FSTEP(a, b2)                                                       \
    {                                                                      \
        float m_  = fmaf(-0.5f, (b2), (a));            /* a-b */           \
        float rn_ = r + fmaf(r, fmaf(r, -m_, -(b2)), (a));                 \
        float y_  = rn_ * C49; float y2_ = y_ * y_; float u_ = y2_ * y2_;  \
        float pl_ = fmaf(u_, -0.15625f, 0.25f);                            \
        r = rn_ - (rn_ * u_) * pl_;                                        \
    }

// emit step: tanh 2-term, divisor corrections first-order, full perc poly
#define ESTEP(a, b2, PS, PC)                                               \
    {                                                                      \
        float b_   = 0.5f * (b2);                                          \
        float tp_  = (a) * fmaf((a) * (a), -0.33333334f, 1.0f);            \
        float te_  = b_ * fmaf(b_ * b_, -0.33333334f, 1.0f);               \
        float q1_  = fmaf(-r, tp_, 1.0f);              /* 1-e1 */          \
        float dp_  = (tp_ * fmaf(-r, r, 1.0f)) * q1_;                      \
        float omr_ = 1.0f - r;                                             \
        float q2_  = fmaf(-te_, omr_, 1.0f);           /* 1-e2 */          \
        float de_  = ((r * (2.0f - r)) * te_) * q2_;                       \
        float rn_  = r + (dp_ - de_);                                      \
        float y_   = rn_ * C49; float y2_ = y_ * y_; float u_ = y2_ * y2_; \
        float pl_  = fmaf(u_, fmaf(u_, 0.1171875f, -0.15625f), 0.25f);     \
        float pcr_ = (rn_ * u_) * pl_;                                     \
        r = rn_ - pcr_;                                                    \
        PS = x1s * dp_;                                                    \
        PC = x1s * pcr_;                                                   \
    }

// consume ring slot + prefetch 4 ahead (crossing into next group via Sn)
#define FQ(RN, mm)                                                         \
    FSTEP(RN.x, RN.y)                                                      \
    RN = ((mm) < 12) ? RD(Sc, (mm) + 4) : RD(Sn, (mm) - 12);

// emit pair (guard m0<12: last needed load at m0=10 -> elements 14,15)
#define EPAIR2(RA, RB, m0)                                                 \
    {                                                                      \
        float psA, pcA, psB, pcB;                                          \
        ESTEP(RA.x, RA.y, psA, pcA)                                        \
        ESTEP(RB.x, RB.y, psB, pcB)                                        \
        if (SIDE) {                                                        \
            *(float4*)(side + 2 * (size_t)(t0 + (m0))) =                   \
                make_float4(psA, pcA, psB, pcB);                           \
        } else {                                                           \
            *(float2*)(out + 6 * (size_t)(t0 + (m0)) + 4)  = make_float2(psA, pcA); \
            *(float2*)(out + 6 * (size_t)(t0 + (m0)) + 10) = make_float2(psB, pcB); \
        }                                                                  \
        sum4 += psA + psB; sq4 = fmaf(psA, psA, sq4); sq4 = fmaf(psB, psB, sq4); \
        sum5 += pcA + pcB; sq5 = fmaf(pcA, pcA, sq5); sq5 = fmaf(pcB, pcB, sq5); \
        if ((m0) < 12) { RA = RD(Se, (m0) + 4); RB = RD(Se, (m0) + 5); }   \
    }

template <bool SIDE>
__global__ __launch_bounds__(256, 2) void scan_kernel(const float4* __restrict__ x4,
                                                      const float* __restrict__ x1p,
                                                      float* __restrict__ out,
                                                      float* __restrict__ side,
                                                      double* __restrict__ sp) {
    __shared__ float2 plane[LDSN];
    __shared__ float cA[NWIN + 1], cB[NWIN + 1], cC[NWIN + 1], cD[NWIN + 1];
    __shared__ double red[4][12];

    const float x1s    = x1p[0];
    const float inv_x1 = 1.0f / x1s;
    const float inv2x  = 2.0f * inv_x1;
    const float rmax   = 320.0f * inv_x1;
    const int k  = blockIdx.x * 256 + threadIdx.x;     // chunk id
    const int kp = threadIdx.x;                        // chunk offset in block
    const char* lbase = (const char*)plane;

    // ---- stage (a,2b) for elements [16k0-640, 16k0+4096+16) + cols0-3 stats
    float s0 = 0, s1 = 0, s2c = 0, s3 = 0, q0 = 0, q1 = 0, q2 = 0, q3 = 0;
    {
        const int g0 = 2048 * blockIdx.x - 320;        // float4 base
        for (int j = 0; j < 10; ++j) {
            int ts = threadIdx.x + 256 * j;
            if (ts < NSTAGE4) {
                int g4 = g0 + ts;
                float4 v = x4[min(max(g4, 0), X4MAX)];
                float pn0 = fmaxf(v.x - v.y, 0.0f), en0 = fmaxf(v.y - v.x, 0.0f);
                float pn1 = fmaxf(v.z - v.w, 0.0f), en1 = fmaxf(v.w - v.z, 0.0f);
                if (g4 < 0) { pn0 = en0 = pn1 = en1 = 0.0f; }
                plane[SWZ(2 * ts)]     = make_float2(pn0 * inv_x1, en0 * inv2x);
                plane[SWZ(2 * ts + 1)] = make_float2(pn1 * inv_x1, en1 * inv2x);
                if (ts >= 320 && ts < 2368) {          // owned emit region
                    s0 += v.x + v.z; q0 = fmaf(v.x, v.x, q0); q0 = fmaf(v.z, v.z, q0);
                    s1 += v.y + v.w; q1 = fmaf(v.y, v.y, q1); q1 = fmaf(v.w, v.w, q1);
                    s2c += pn0 + pn1; q2 = fmaf(pn0, pn0, q2); q2 = fmaf(pn1, pn1, q2);
                    s3 += en0 + en1; q3 = fmaf(en0, en0, q3); q3 = fmaf(en1, en1, q3);
                }
            }
        }
    }
    __syncthreads();

    // ---- per-window drift-cubic coeffs from staged plane (linear tanh) ----
    for (int wl = threadIdx.x; wl < NWIN; wl += 256) {
        const int Sw = SWZ(16 * wl) << 3;
        float Sa = 0, Sa2 = 0, Sb = 0, Sb2 = 0;
#pragma unroll
        for (int mm = 0; mm < 16; ++mm) {
            float2 p = RD(Sw, mm);
            Sa += p.x; Sa2 = fmaf(p.x, p.x, Sa2);
            Sb += p.y; Sb2 = fmaf(p.y, p.y, Sb2);
        }
        float Tp = Sa, Qp = Sa2, Te = 0.5f * Sb, Qe = 0.25f * Sb2;
        cA[wl] = Tp;
        cB[wl] = 2.0f * (Qe - Te) - Qp;
        cC[wl] = Te - Tp - 3.0f * Qe;
        cD[wl] = Qp + Qe;
    }
    __syncthreads();

    // ---- coarse phase: windows k-40..k-9 = local wl kp..kp+31 ----
    float4 c0 = WLD(0), c1 = WLD(1), c2 = WLD(2), c3 = WLD(3),
           c4 = WLD(4), c5 = WLD(5), c6 = WLD(6), c7 = WLD(7);
    float r = 0.0f;
    CGRP_R(0) CGRP_R(8) CGRP_R(16) CGRP_L              // 32 coarse windows

    // ---- exact tail: 128 steps (local elements 16kp+512 .. +640) ----
    float2 r0, r1, r2, r3;
    {
        const int S0 = SWZ(16 * kp + 512) << 3;
        r0 = RD(S0, 0); r1 = RD(S0, 1); r2 = RD(S0, 2); r3 = RD(S0, 3);
    }
#pragma unroll 1
    for (int B = 0; B < NTAIL; B += 16) {
        const int W0 = 16 * kp + 512 + B;
        const int Sc = SWZ(W0) << 3;
        const int Sn = SWZ(W0 + 16) << 3;
        FQ(r0, 0)  FQ(r1, 1)  FQ(r2, 2)  FQ(r3, 3)
        FQ(r0, 4)  FQ(r1, 5)  FQ(r2, 6)  FQ(r3, 7)
        FQ(r0, 8)  FQ(r1, 9)  FQ(r2, 10) FQ(r3, 11)
        FQ(r0, 12) FQ(r1, 13) FQ(r2, 14) FQ(r3, 15)
    }

    // ---- exact emit: 16 steps (local elements 16kp+640 ..) ----
    float sum4 = 0, sum5 = 0, sq4 = 0, sq5 = 0;
    const int t0 = 16 * k;
    const int Se = SWZ(16 * kp + 512 + NTAIL) << 3;
    EPAIR2(r0, r1, 0)  EPAIR2(r2, r3, 2)
    EPAIR2(r0, r1, 4)  EPAIR2(r2, r3, 6)
    EPAIR2(r0, r1, 8)  EPAIR2(r2, r3, 10)
    EPAIR2(r0, r1, 12) EPAIR2(r2, r3, 14)

    // ---- block reduction: 12 stat channels -> per-block partials ----
    double vv[12] = {s0, s1, s2c, s3, sum4, sum5,
                     q0, q1, q2, q3, sq4, sq5};
    const int wid = threadIdx.x >> 6, lane = threadIdx.x & 63;
#pragma unroll
    for (int c = 0; c < 12; ++c) {
        double val = vv[c];
        for (int off = 32; off > 0; off >>= 1) val += __shfl_down(val, off, 64);
        if (lane == 0) red[wid][c] = val;
    }
    __syncthreads();
    if (threadIdx.x < 12) {
        int c = threadIdx.x;
        sp[c * 512 + blockIdx.x] = red[0][c] + red[1][c] + red[2][c] + red[3][c];
    }
}

// ---------------- finalize: reduce partials -> musig ----------------
__global__ __launch_bounds__(256) void finalize_kernel(const double* __restrict__ sp,
                                                       float* __restrict__ musig) {
    __shared__ double red[12][4];
    const int t = threadIdx.x, lane = t & 63, wid = t >> 6;
#pragma unroll
    for (int c = 0; c < 12; ++c) {
        double v = sp[c * 512 + t] + sp[c * 512 + 256 + t];
        for (int off = 32; off > 0; off >>= 1) v += __shfl_down(v, off, 64);
        if (lane == 0) red[c][wid] = v;
    }
    __syncthreads();
    if (t < 6) {
        double sum = red[t][0] + red[t][1] + red[t][2] + red[t][3];
        double sq  = red[6 + t][0] + red[6 + t][1] + red[6 + t][2] + red[6 + t][3];
        double n = (double)T_TOTAL;
        double mu = sum / n;
        double var = (sq - sum * sum / n) / (n - 1.0);
        musig[t] = (float)mu;
        musig[6 + t] = (float)(1.0 / sqrt(var));
    }
}

// ---------------- normalize (plain float4 stores) ----------------
template <bool SIDE>
__global__ __launch_bounds__(256) void normalize_kernel(const float4* __restrict__ xp4,
                                                        const float4* __restrict__ side4,
                                                        float* __restrict__ out,
                                                        const float* __restrict__ musig) {
    float mu[6], is[6];
#pragma unroll
    for (int c = 0; c < 6; ++c) { mu[c] = musig[c]; is[c] = musig[6 + c]; }

    int idx = blockIdx.x * blockDim.x + threadIdx.x;
    int stride = gridDim.x * blockDim.x;
    for (int p = idx; p < T_TOTAL / 2; p += stride) {
        float4 xv = xp4[p];
        float* o = out + 12 * (size_t)p;
        float4 sv;
        if (SIDE) {
            sv = side4[p];
        } else {
            float2 a = *(const float2*)(o + 4);
            float2 b = *(const float2*)(o + 10);
            sv = make_float4(a.x, a.y, b.x, b.y);
        }
        float pn0 = fmaxf(xv.x - xv.y, 0.0f), en0 = fmaxf(xv.y - xv.x, 0.0f);
        float pn1 = fmaxf(xv.z - xv.w, 0.0f), en1 = fmaxf(xv.w - xv.z, 0.0f);
        float4 o0 = {(xv.x - mu[0]) * is[0], (xv.y - mu[1]) * is[1],
                     (pn0 - mu[2]) * is[2], (en0 - mu[3]) * is[3]};
        float4 o1 = {(sv.x - mu[4]) * is[4], (sv.y - mu[5]) * is[5],
                     (xv.z - mu[0]) * is[0], (xv.w - mu[1]) * is[1]};
        float4 o2 = {(pn1 - mu[2]) * is[2], (en1 - mu[3]) * is[3],
                     (sv.z - mu[4]) * is[4], (sv.w - mu[5]) * is[5]};
        *(float4*)(o + 0) = o0;
        *(float4*)(o + 4) = o1;
        *(float4*)(o + 8) = o2;
    }
}

extern "C" void kernel_launch(void* const* d_in, const int* in_sizes, int n_in,
                              void* d_out, int out_size, void* d_ws, size_t ws_size,
                              hipStream_t stream) {
    const float4* x4 = (const float4*)d_in[0];
    const float* x1 = (const float*)d_in[1];
    float* out = (float*)d_out;
    char* ws = (char*)d_ws;
    double* sp = (double*)(ws + OFF_SP);
    float* musig = (float*)(ws + OFF_MUSIG);
    float* side = (float*)(ws + OFF_SIDE);

    const bool use_side = ws_size >= (size_t)OFF_SIDE + (size_t)T_TOTAL * 8;

    if (use_side) {
        scan_kernel<true><<<NBLOCKS, THREADS, 0, stream>>>(x4, x1, out, side, sp);
        finalize_kernel<<<1, 256, 0, stream>>>(sp, musig);
        normalize_kernel<true><<<2048, 256, 0, stream>>>(x4, (const float4*)side, out, musig);
    } else {
        scan_kernel<false><<<NBLOCKS, THREADS, 0, stream>>>(x4, x1, out, side, sp);
        finalize_kernel<<<1, 256, 0, stream>>>(sp, musig);
        normalize_kernel<false><<<2048, 256, 0, stream>>>(x4, (const float4*)side, out, musig);
    }
}